// Round 3
// baseline (111.412 us; speedup 1.0000x reference)
//
#include <hip/hip_runtime.h>

#define FRAME 160
#define ORDER 12
#define NFRAMES (4096 * 15)
#define EPL 10   // elements per lane
#define FPW 4    // frames per wave (16 lanes each)

template<int CTRL>
__device__ __forceinline__ float dppf(float v) {
    return __int_as_float(__builtin_amdgcn_update_dpp(
        0, __float_as_int(v), CTRL, 0xF, 0xF, true));
}

// Sum across each 16-lane row, pure-VALU DPP; result bit-identical in all
// 16 lanes (xor1/xor2 butterflies + mirror/half_mirror, add-commutative).
__device__ __forceinline__ float rowsum16(float v) {
    v += dppf<0xB1>(v);    // quad_perm [1,0,3,2]  : lane ^= 1
    v += dppf<0x4E>(v);    // quad_perm [2,3,0,1]  : lane ^= 2
    v += dppf<0x140>(v);   // row_mirror           : quad q <-> 3-q
    v += dppf<0x141>(v);   // row_half_mirror      : quad q <-> q^1
    return v;
}

__global__ __launch_bounds__(256) void ResidualEmbedding_70798240907390_kernel(
    const int* __restrict__ bits, const float* __restrict__ pcm,
    const float* __restrict__ alpha_p, float* __restrict__ out)
{
    const int wave = threadIdx.x >> 6;
    const int lane = threadIdx.x & 63;
    const int g    = lane >> 4;    // frame group within wave
    const int s    = lane & 15;    // sub-lane within group
    const int wf0  = (blockIdx.x * 4 + wave) * FPW;
    const int f_id = wf0 + g;

    __shared__ float s_frame[4][FPW][FRAME];   // 10 KB
    __shared__ float s_a[4][FPW][16];          // 1 KB

    // Stage 4 frames/wave = 640 floats = 160 float4, coalesced.
    {
        const float4* src = (const float4*)(pcm + (size_t)wf0 * FRAME);
        float4* dst = (float4*)&s_frame[wave][0][0];
        dst[lane]      = src[lane];
        dst[lane + 64] = src[lane + 64];
        if (lane < 32) dst[lane + 128] = src[lane + 128];
    }
    __syncthreads();
    const float* xf = &s_frame[wave][g][0];

    const int p0 = s * EPL;
    const float w2p = 6.2831853071795864769f / 159.0f;   // hanning(160)

    // f[p]=xw[p+1], b[p]=xw[p], p=0..158; position 159 zero (invariant).
    float F[EPL], B[EPL];
    float dp0 = 0.0f, dp1 = 0.0f;
    float wprev = 0.5f - 0.5f * __cosf(w2p * (float)p0);
#pragma unroll
    for (int t = 0; t < EPL; ++t) {
        int p = p0 + t;
        float wnext = 0.5f - 0.5f * __cosf(w2p * (float)(p + 1));
        if (p < FRAME - 1) {
            float b0 = xf[p] * wprev;
            float f0 = xf[p + 1] * wnext;
            F[t] = f0; B[t] = b0;
            dp0 = fmaf(f0, f0, dp0);
            dp1 = fmaf(b0, b0, dp1);
        } else { F[t] = 0.0f; B[t] = 0.0f; }
        wprev = wnext;
    }
    float den = rowsum16(dp0 + dp1);

    // a (lane s holds a[s]) and its pivot-reversal ar[s] = a[i+1-s].
    float a  = (s == 0) ? 1.0f : 0.0f;
    float ar = (s == 1) ? 1.0f : 0.0f;
    float cpart = 0.0f;        // corr partial from previous iteration
    float denScaled = 0.0f;    // (1-r^2)*den_prev

#pragma unroll
    for (int i = 0; i < ORDER; ++i) {
        // numerator = sum f*b (invalid tail slots are zero -> maskless)
        float q0 = 0.0f, q1 = 0.0f;
#pragma unroll
        for (int t = 0; t < EPL; t += 2) {
            q0 = fmaf(F[t],     B[t],     q0);
            q1 = fmaf(F[t + 1], B[t + 1], q1);
        }
        float num = rowsum16(q0 + q1);
        if (i > 0) den = denScaled - rowsum16(cpart);   // independent DPP chain
        float r = -2.0f * num * __builtin_amdgcn_rcpf(den);

        // a[:i+2] += r*a[:i+2][::-1] without any shuffle:
        //   a' = a + r*ar ; ar' = (ar + r*a) shifted one lane up (pivot+1)
        float a_new  = fmaf(r, ar, a);
        float ar_new = fmaf(r, a, ar);
        a  = a_new;
        ar = dppf<0x111>(ar_new);          // row_shr:1, lane0 <- 0

        // f += r*b ; b += r*f_old
        float nF[EPL], nB[EPL];
#pragma unroll
        for (int t = 0; t < EPL; ++t) {
            nF[t] = fmaf(r, B[t], F[t]);
            nB[t] = fmaf(r, F[t], B[t]);
        }

        // corr = f'[0]^2 + b'[last]^2 (folded into next iteration's reduce)
        const int pe = 158 - i;                 // compile-time (full unroll)
        const int SL = pe / EPL, SS = pe % EPL;
        float fe = (s == 0)  ? nF[0]  : 0.0f;
        float be = (s == SL) ? nB[SS] : 0.0f;
        cpart = fmaf(fe, fe, be * be);
        denScaled = fmaf(-r * r, den, den);     // (1-r^2)*den

        // f = f'[1:]  (row_shl:1 brings lane s+1's nF[0]; lane15 -> 0 = pos159)
        float up = dppf<0x101>(nF[0]);
#pragma unroll
        for (int t = 0; t < EPL - 1; ++t) F[t] = nF[t + 1];
        F[EPL - 1] = up;
        // b = b'[:-1] (zero newly-invalid slot; keeps maskless-dot invariant)
#pragma unroll
        for (int t = 0; t < EPL; ++t) B[t] = nB[t];
        B[SS] = (s == SL) ? 0.0f : B[SS];
    }

    // Broadcast a[0..12] within the group via LDS bounce.
    s_a[wave][g][s] = a;
    __syncthreads();
    float ak[ORDER + 1];
#pragma unroll
    for (int k = 0; k <= ORDER; ++k) ak[k] = s_a[wave][g][k];

    // Raw-sample window: xr[j] = x[p0 - 12 + j], j = 0..21.
    float xr[EPL + ORDER];
#pragma unroll
    for (int j = 0; j < EPL + ORDER; ++j) {
        int m = p0 - ORDER + j;
        xr[j] = (m >= 0) ? xf[m] : 0.0f;
    }

    const float ac = alpha_p[0] * (2.0f * (float)bits[f_id] - 1.0f);
    float res[EPL];
#pragma unroll
    for (int t = 0; t < EPL; ++t) {
        float acc = 0.0f;
#pragma unroll
        for (int k = 0; k <= ORDER; ++k)
            acc = fmaf(ak[k], xr[ORDER + t - k], acc);   // res[n]=sum a[k]x[n-k]
        res[t] = fmaf(ac, acc, xr[ORDER + t]);           // pcm + alpha*res*chip
    }
    float2* og = (float2*)(out + (size_t)f_id * FRAME + p0);
#pragma unroll
    for (int t = 0; t < EPL / 2; ++t)
        og[t] = make_float2(res[2 * t], res[2 * t + 1]);
}

extern "C" void kernel_launch(void* const* d_in, const int* in_sizes, int n_in,
                              void* d_out, int out_size, void* d_ws, size_t ws_size,
                              hipStream_t stream) {
    const int*   bits  = (const int*)d_in[0];
    const float* pcm   = (const float*)d_in[1];
    const float* alpha = (const float*)d_in[2];
    float*       out   = (float*)d_out;

    dim3 grid(NFRAMES / 16), block(256);
    hipLaunchKernelGGL(ResidualEmbedding_70798240907390_kernel, grid, block, 0, stream,
                       bits, pcm, alpha, out);
}